// Round 14
// baseline (46.350 us; speedup 1.0000x reference)
//
#include <hip/hip_runtime.h>

// Cost volume: corr[b, dyi*9+dxi, y, x] = sum_c f1[b,c,y,x] * f2[b,c,y+dyi-4,x+dxi-4]
// (OOB f2 = 0). B=4, C=256, H=W=96, patch 9x9.
//
// Round 14 = round 13 with main's latency chain flattened:
//  - ONE dy per wave (was 3 in a serial loop). Block = (b, y, mt, dy-triplet),
//    3 waves; wave w owns dy = dyt*3+w. All loads (64 A-dwords + 16 B-frags)
//    issue as one batch -> one latency round-trip per wave (was ~4 serial).
//  - Grid 2304 -> 6912 blocks (= 8*864, bijective XCD swizzle; mt fastest,
//    then dyt, then y: neighbors share f1/f2 rows in L2). 81 waves/CU offered.
//  - LDS tile [27][20] (2.2 KB), writeout 27 coalesced 64B rows per block.
//  - pack_f2 (f2-only channel-major f16 repack) unchanged from R13.

typedef _Float16 f16x8 __attribute__((ext_vector_type(8)));
typedef float f32x4 __attribute__((ext_vector_type(4)));

#define NB 4
#define NC 256
#define NH 96
#define NW 96
#define NP 9
#define PLANE (NH * NW)                       // 9216
#define TENS (NB * NH * NW * NC)              // 9,437,184 f16 (f2 only)
#define WS_NEED ((unsigned long long)TENS * 2ull)  // 18,874,368 B
#define TPT4 (TENS / 32)                      // 294,912 pack threads
#define PACK_BLK (TPT4 / 256)                 // 1152
#define MAIN_BLK 6912                         // 4b * 96y * 3dyt * 6mt
#define CGSTR (NW * 8)                        // 768 f16 per cg-plane
#define ROWSTR (32 * CGSTR)                   // 24576 f16 per (b,y) row
#define LPAD 37                               // fallback kernel pad

// ---------- prepass: f2 f32 [b][c][y][x] -> f16 [b][y][cg][x][8] ------------
__global__ __launch_bounds__(256) void pack_f2(const float* __restrict__ f2,
                                               _Float16* __restrict__ ws)
{
    const int e   = blockIdx.x * 256 + threadIdx.x;   // 0 .. 294,911
    const int row = e / 768;                          // b*96 + y   (384)
    const int q   = e % 768;
    const int cg  = q / 24;                           // 0..31
    const int x4  = q % 24;                           // lane-fastest (coalesced)
    const int b   = row / NH;
    const int y   = row % NH;

    const float* sp = f2 + ((size_t)(b * NC + cg * 8) * NH + y) * NW + x4 * 4;
    float vv[8][4];
#pragma unroll
    for (int j = 0; j < 8; ++j) {
        const float4 v = *(const float4*)(sp + (size_t)j * PLANE);
        vv[j][0] = v.x; vv[j][1] = v.y; vv[j][2] = v.z; vv[j][3] = v.w;
    }
    _Float16* dp = ws + ((size_t)row * 32 + cg) * CGSTR + (size_t)x4 * 32;
#pragma unroll
    for (int xi = 0; xi < 4; ++xi) {
        f16x8 o;
#pragma unroll
        for (int j = 0; j < 8; ++j) o[j] = (_Float16)vv[j][xi];
        *(f16x8*)(dp + xi * 8) = o;
    }
}

// ---------- main: MFMA banded Gram, one dy per wave --------------------------
__global__ __launch_bounds__(192) void costvol_mfma(const float* __restrict__ f1,
                                                    const _Float16* __restrict__ f2p,
                                                    float* __restrict__ out)
{
    __shared__ float lds[27][20];                 // 2160 B

    const int bid = blockIdx.x;
    const int swz = (bid & 7) * (MAIN_BLK / 8) + (bid >> 3);
    const int mt  = swz % 6;                      // fastest: mt (L2 row reuse)
    const int dyt = (swz / 6) % 3;
    const int y   = (swz / 18) % 96;
    const int b   = swz / 1728;

    const int w    = threadIdx.x >> 6;            // wave 0..2: dy = dyt*3+w
    const int lane = threadIdx.x & 63;
    const int lr   = lane & 15;
    const int lg   = lane >> 4;
    const int m0   = mt * 16;

    const int dy = dyt * 3 + w;
    const int y2 = y + dy - 4;

    // A frags direct from f32: c = lg*8 + ks*32 + j; 16 lanes share 64B lines
    const float* pa32 = f1 + ((size_t)(b * NC + lg * 8) * NH + y) * NW + (m0 + lr);
    f16x8 a[8];
#pragma unroll
    for (int ks = 0; ks < 8; ++ks) {
        f16x8 o;
#pragma unroll
        for (int j = 0; j < 8; ++j)
            o[j] = (_Float16)pa32[(size_t)(ks * 32 + j) * PLANE];
        a[ks] = o;
    }

    const int n0a = m0 - 8 + lr;                  // x' tile 0 (may be <0)
    const int n0b = m0 + 8 + lr;                  // x' tile 1 (may be >=96)
    const bool inA = (n0a >= 0);
    const bool inB = (n0b < 96);
    const f16x8 bz = {};

    f32x4 acc0 = {0.f, 0.f, 0.f, 0.f};
    f32x4 acc1 = {0.f, 0.f, 0.f, 0.f};

    if (y2 >= 0 && y2 < 96) {
        const _Float16* base = f2p + (size_t)(b * 96 + y2) * ROWSTR + (size_t)lg * CGSTR;
        const _Float16* pba  = base + (ptrdiff_t)n0a * 8;
        const _Float16* pbb  = base + (ptrdiff_t)n0b * 8;
        f16x8 B0[8], B1[8];
#pragma unroll
        for (int ks = 0; ks < 8; ++ks) {          // issue all 16 loads first
            B0[ks] = inA ? *(const f16x8*)(pba + (size_t)ks * 4 * CGSTR) : bz;
            B1[ks] = inB ? *(const f16x8*)(pbb + (size_t)ks * 4 * CGSTR) : bz;
        }
#pragma unroll
        for (int ks = 0; ks < 8; ++ks) {
            acc0 = __builtin_amdgcn_mfma_f32_16x16x32_f16(a[ks], B0[ks], acc0, 0, 0, 0);
            acc1 = __builtin_amdgcn_mfma_f32_16x16x32_f16(a[ks], B1[ks], acc1, 0, 0, 0);
        }
    }

    // stage to LDS: D row m = m0+lg*4+reg, col n = lr; disjoint dx0/dx1
#pragma unroll
    for (int reg = 0; reg < 4; ++reg) {
        const int mrow = lg * 4 + reg;
        const int dx0  = lr - mrow - 4;           // tile0: x' = m0-8+lr
        const int dx1  = dx0 + 16;                // tile1: x' = m0+8+lr
        if (dx0 >= 0 && dx0 <= 8) lds[w * 9 + dx0][mrow] = acc0[reg];
        if (dx1 >= 0 && dx1 <= 8) lds[w * 9 + dx1][mrow] = acc1[reg];
    }

    __syncthreads();

    // coalesced writeout: lds row r -> out plane b*81 + dyt*27 + r, 64B line
    const int r = threadIdx.x >> 2;
    const int q = (threadIdx.x & 3) * 4;
    if (r < 27) {
        const float4 v = make_float4(lds[r][q], lds[r][q + 1],
                                     lds[r][q + 2], lds[r][q + 3]);
        *(float4*)(out + ((size_t)(b * 81 + dyt * 27 + r) * PLANE) + y * 96 + m0 + q) = v;
    }
}

// ---------- fallback: round-2 f32 kernel (if ws too small) ------------------
__global__ __launch_bounds__(256) void costvol_f32(const float* __restrict__ f1,
                                                   const float* __restrict__ f2,
                                                   float* __restrict__ out)
{
    __shared__ float lds[2 * 64 * LPAD];
    const int bid = blockIdx.x;
    const int swz = (bid & 7) * (1296 / 8) + (bid >> 3);
    const int dyi = swz % NP;
    const int g   = swz / NP;
    const int w    = threadIdx.x >> 6;
    const int lane = threadIdx.x & 63;
    const int chk = g * 64 + lane;
    const int b   = chk / (NH * 24);
    const int rem = chk - b * (NH * 24);
    const int y   = rem / 24;
    const int x0  = (rem - y * 24) * 4;
    const int y2  = y + dyi - 4;

    float acc[NP][4];
#pragma unroll
    for (int i = 0; i < NP; ++i)
#pragma unroll
        for (int j = 0; j < 4; ++j) acc[i][j] = 0.f;

    if (y2 >= 0 && y2 < NH) {
        const float* p1 = f1 + ((size_t)(b * NC + w * 64) * NH + y) * NW + x0;
        const float* p2 = f2 + ((size_t)(b * NC + w * 64) * NH + y2) * NW + x0;
        const bool hasL = (x0 >= 4);
        const bool hasR = (x0 <= NW - 8);
#pragma unroll 4
        for (int c = 0; c < 64; ++c) {
            const float4 av = *(const float4*)p1;
            const float4 Lv = hasL ? *(const float4*)(p2 - 4) : make_float4(0.f, 0.f, 0.f, 0.f);
            const float4 Mv = *(const float4*)(p2);
            const float4 Rv = hasR ? *(const float4*)(p2 + 4) : make_float4(0.f, 0.f, 0.f, 0.f);
            const float wv[12] = {Lv.x, Lv.y, Lv.z, Lv.w, Mv.x, Mv.y, Mv.z, Mv.w,
                                  Rv.x, Rv.y, Rv.z, Rv.w};
            const float aa[4] = {av.x, av.y, av.z, av.w};
#pragma unroll
            for (int dxi = 0; dxi < NP; ++dxi)
#pragma unroll
                for (int j = 0; j < 4; ++j) acc[dxi][j] += aa[j] * wv[dxi + j];
            p1 += PLANE;
            p2 += PLANE;
        }
    }

    float* reg0 = &lds[0 * 64 * LPAD + lane * LPAD];
    float* reg1 = &lds[1 * 64 * LPAD + lane * LPAD];
    if (w >= 2) {
        float* dst = (w == 2) ? reg0 : reg1;
#pragma unroll
        for (int dxi = 0; dxi < NP; ++dxi)
#pragma unroll
            for (int j = 0; j < 4; ++j) dst[dxi * 4 + j] = acc[dxi][j];
    }
    __syncthreads();
    if (w < 2) {
        const float* src = (w == 0) ? reg0 : reg1;
#pragma unroll
        for (int dxi = 0; dxi < NP; ++dxi)
#pragma unroll
            for (int j = 0; j < 4; ++j) acc[dxi][j] += src[dxi * 4 + j];
    }
    __syncthreads();
    if (w == 1) {
#pragma unroll
        for (int dxi = 0; dxi < NP; ++dxi)
#pragma unroll
            for (int j = 0; j < 4; ++j) reg0[dxi * 4 + j] = acc[dxi][j];
    }
    __syncthreads();
    if (w == 0) {
#pragma unroll
        for (int dxi = 0; dxi < NP; ++dxi)
#pragma unroll
            for (int j = 0; j < 4; ++j) acc[dxi][j] += reg0[dxi * 4 + j];
        float* ob = out + ((size_t)(b * 81 + dyi * 9) * NH + y) * NW + x0;
#pragma unroll
        for (int dxi = 0; dxi < NP; ++dxi) {
            *(float4*)ob = make_float4(acc[dxi][0], acc[dxi][1], acc[dxi][2], acc[dxi][3]);
            ob += PLANE;
        }
    }
}

extern "C" void kernel_launch(void* const* d_in, const int* in_sizes, int n_in,
                              void* d_out, int out_size, void* d_ws, size_t ws_size,
                              hipStream_t stream) {
    const float* f1 = (const float*)d_in[0];
    const float* f2 = (const float*)d_in[1];
    float* out = (float*)d_out;
    if (ws_size >= WS_NEED) {
        _Float16* ws = (_Float16*)d_ws;
        pack_f2<<<dim3(PACK_BLK, 1, 1), dim3(256, 1, 1), 0, stream>>>(f2, ws);
        costvol_mfma<<<dim3(MAIN_BLK, 1, 1), dim3(192, 1, 1), 0, stream>>>(f1, ws, out);
    } else {
        costvol_f32<<<dim3(1296, 1, 1), dim3(256, 1, 1), 0, stream>>>(f1, f2, out);
    }
}

// Round 15
// 38.520 us; speedup vs baseline: 1.2033x; 1.2033x over previous
//
#include <hip/hip_runtime.h>

// Cost volume: corr[b, dyi*9+dxi, y, x] = sum_c f1[b,c,y,x] * f2[b,c,y+dyi-4,x+dxi-4]
// (OOB f2 = 0). B=4, C=256, H=W=96, patch 9x9.
//
// Round 15 = round 13 (best: 41.2us) + block-level LDS staging of the A-tile.
//  R14 proved the A-phase (64 scalar loads + 64 cvt per lane) is ~10us of
//  main's ~25us: replicating it 3x (one dy/wave) cost +20us. Here the block's
//  192 threads stage the 16KB f32 A-tile cooperatively (1024 coalesced
//  float4 = ~6/thread), cvt to f16, ds_write to [x][c] (row 272 f16 = 544B
//  -> 4-way-max ds_read_b128 conflicts), barrier, each lane ds_reads its 8
//  fragments. Out-staging reuses the same LDS after a barrier.
//  Pack (f2-only), B-path, writeout, swizzles unchanged from R13.

typedef _Float16 f16x8 __attribute__((ext_vector_type(8)));
typedef float f32x4 __attribute__((ext_vector_type(4)));

#define NB 4
#define NC 256
#define NH 96
#define NW 96
#define NP 9
#define PLANE (NH * NW)                       // 9216
#define TENS (NB * NH * NW * NC)              // 9,437,184 f16 (f2 only)
#define WS_NEED ((unsigned long long)TENS * 2ull)  // 18,874,368 B
#define TPT4 (TENS / 32)                      // 294,912 pack threads
#define PACK_BLK (TPT4 / 256)                 // 1152
#define MAIN_BLK 2304                         // 4b * 96y * 6mt
#define CGSTR (NW * 8)                        // 768 f16 per cg-plane
#define ROWSTR (32 * CGSTR)                   // 24576 f16 per (b,y) row
#define AROW 272                              // A-tile row stride in f16 (544 B)
#define LPAD 37                               // fallback kernel pad

// ---------- prepass: f2 f32 [b][c][y][x] -> f16 [b][y][cg][x][8] ------------
__global__ __launch_bounds__(256) void pack_f2(const float* __restrict__ f2,
                                               _Float16* __restrict__ ws)
{
    const int e   = blockIdx.x * 256 + threadIdx.x;   // 0 .. 294,911
    const int row = e / 768;                          // b*96 + y   (384)
    const int q   = e % 768;
    const int cg  = q / 24;                           // 0..31
    const int x4  = q % 24;                           // lane-fastest (coalesced)
    const int b   = row / NH;
    const int y   = row % NH;

    const float* sp = f2 + ((size_t)(b * NC + cg * 8) * NH + y) * NW + x4 * 4;
    float vv[8][4];
#pragma unroll
    for (int j = 0; j < 8; ++j) {
        const float4 v = *(const float4*)(sp + (size_t)j * PLANE);
        vv[j][0] = v.x; vv[j][1] = v.y; vv[j][2] = v.z; vv[j][3] = v.w;
    }
    _Float16* dp = ws + ((size_t)row * 32 + cg) * CGSTR + (size_t)x4 * 32;
#pragma unroll
    for (int xi = 0; xi < 4; ++xi) {
        f16x8 o;
#pragma unroll
        for (int j = 0; j < 8; ++j) o[j] = (_Float16)vv[j][xi];
        *(f16x8*)(dp + xi * 8) = o;
    }
}

// ---------- main: MFMA banded Gram, LDS-staged A -----------------------------
__global__ __launch_bounds__(192) void costvol_mfma(const float* __restrict__ f1,
                                                    const _Float16* __restrict__ f2p,
                                                    float* __restrict__ out)
{
    __shared__ char shbuf[16 * AROW * 2];         // 8704 f16 = 17,408 B
    _Float16* lds_a = (_Float16*)shbuf;           // [x=16][c] rows, stride AROW
    float (*ldso)[20] = (float(*)[20])shbuf;      // out staging (6480 B), reused

    const int bid = blockIdx.x;
    const int swz = (bid & 7) * (MAIN_BLK / 8) + (bid >> 3);
    const int mt  = swz % 6;
    const int y   = (swz / 6) % 96;
    const int b   = swz / 576;

    const int w    = threadIdx.x >> 6;            // wave 0..2 = dy-triplet
    const int lane = threadIdx.x & 63;
    const int lr   = lane & 15;
    const int lg   = lane >> 4;
    const int m0   = mt * 16;

    // --- cooperative A staging: 1024 float4 tasks over 192 threads ---------
#pragma unroll
    for (int i = 0; i < 6; ++i) {
        const int task = threadIdx.x + i * 192;   // 0..1151
        if (task < 1024) {
            const int c  = task >> 2;
            const int xq = task & 3;
            const float4 v = *(const float4*)(
                f1 + ((size_t)(b * NC + c) * NH + y) * NW + m0 + xq * 4);
            _Float16* d0 = lds_a + (size_t)(xq * 4) * AROW + c;
            d0[0 * AROW] = (_Float16)v.x;
            d0[1 * AROW] = (_Float16)v.y;
            d0[2 * AROW] = (_Float16)v.z;
            d0[3 * AROW] = (_Float16)v.w;
        }
    }
    __syncthreads();

    // --- fragment read: lane (lr,lg), ks: 8 f16 at row lr, col ks*32+lg*8 --
    f16x8 a[8];
    {
        const _Float16* ap = lds_a + (size_t)lr * AROW + lg * 8;
#pragma unroll
        for (int ks = 0; ks < 8; ++ks) a[ks] = *(const f16x8*)(ap + ks * 32);
    }
    __syncthreads();                              // lds_a dead; ldso reuses it

    const int n0a = m0 - 8 + lr;                  // x' tile 0 (may be <0)
    const int n0b = m0 + 8 + lr;                  // x' tile 1 (may be >=96)
    const bool inA = (n0a >= 0);
    const bool inB = (n0b < 96);
    const f16x8 bz = {};

#pragma unroll 1
    for (int i = 0; i < 3; ++i) {
        const int dy = w * 3 + i;
        const int y2 = y + dy - 4;
        f32x4 acc0 = {0.f, 0.f, 0.f, 0.f};
        f32x4 acc1 = {0.f, 0.f, 0.f, 0.f};

        if (y2 >= 0 && y2 < 96) {
            const _Float16* base = f2p + (size_t)(b * 96 + y2) * ROWSTR + (size_t)lg * CGSTR;
            const _Float16* pba  = base + (ptrdiff_t)n0a * 8;
            const _Float16* pbb  = base + (ptrdiff_t)n0b * 8;
            f16x8 B0[8], B1[8];
#pragma unroll
            for (int ks = 0; ks < 8; ++ks) {      // issue all 16 loads first
                B0[ks] = inA ? *(const f16x8*)(pba + (size_t)ks * 4 * CGSTR) : bz;
                B1[ks] = inB ? *(const f16x8*)(pbb + (size_t)ks * 4 * CGSTR) : bz;
            }
#pragma unroll
            for (int ks = 0; ks < 8; ++ks) {
                acc0 = __builtin_amdgcn_mfma_f32_16x16x32_f16(a[ks], B0[ks], acc0, 0, 0, 0);
                acc1 = __builtin_amdgcn_mfma_f32_16x16x32_f16(a[ks], B1[ks], acc1, 0, 0, 0);
            }
        }

        // stage to LDS: D row m = m0+lg*4+reg, col n = lr; disjoint dx0/dx1
#pragma unroll
        for (int reg = 0; reg < 4; ++reg) {
            const int mrow = lg * 4 + reg;
            const int dx0  = lr - mrow - 4;       // tile0: x' = m0-8+lr
            const int dx1  = dx0 + 16;            // tile1: x' = m0+8+lr
            if (dx0 >= 0 && dx0 <= 8) ldso[dy * 9 + dx0][mrow] = acc0[reg];
            if (dx1 >= 0 && dx1 <= 8) ldso[dy * 9 + dx1][mrow] = acc1[reg];
        }
    }

    __syncthreads();

    // coalesced writeout: row r = dy*9+dx -> 64B line
    const int q = (threadIdx.x & 3) * 4;
#pragma unroll
    for (int r = threadIdx.x >> 2; r < 81; r += 48) {
        const float4 v = make_float4(ldso[r][q], ldso[r][q + 1],
                                     ldso[r][q + 2], ldso[r][q + 3]);
        *(float4*)(out + ((size_t)(b * 81 + r) * PLANE) + y * 96 + m0 + q) = v;
    }
}

// ---------- fallback: round-2 f32 kernel (if ws too small) ------------------
__global__ __launch_bounds__(256) void costvol_f32(const float* __restrict__ f1,
                                                   const float* __restrict__ f2,
                                                   float* __restrict__ out)
{
    __shared__ float lds[2 * 64 * LPAD];
    const int bid = blockIdx.x;
    const int swz = (bid & 7) * (1296 / 8) + (bid >> 3);
    const int dyi = swz % NP;
    const int g   = swz / NP;
    const int w    = threadIdx.x >> 6;
    const int lane = threadIdx.x & 63;
    const int chk = g * 64 + lane;
    const int b   = chk / (NH * 24);
    const int rem = chk - b * (NH * 24);
    const int y   = rem / 24;
    const int x0  = (rem - y * 24) * 4;
    const int y2  = y + dyi - 4;

    float acc[NP][4];
#pragma unroll
    for (int i = 0; i < NP; ++i)
#pragma unroll
        for (int j = 0; j < 4; ++j) acc[i][j] = 0.f;

    if (y2 >= 0 && y2 < NH) {
        const float* p1 = f1 + ((size_t)(b * NC + w * 64) * NH + y) * NW + x0;
        const float* p2 = f2 + ((size_t)(b * NC + w * 64) * NH + y2) * NW + x0;
        const bool hasL = (x0 >= 4);
        const bool hasR = (x0 <= NW - 8);
#pragma unroll 4
        for (int c = 0; c < 64; ++c) {
            const float4 av = *(const float4*)p1;
            const float4 Lv = hasL ? *(const float4*)(p2 - 4) : make_float4(0.f, 0.f, 0.f, 0.f);
            const float4 Mv = *(const float4*)(p2);
            const float4 Rv = hasR ? *(const float4*)(p2 + 4) : make_float4(0.f, 0.f, 0.f, 0.f);
            const float wv[12] = {Lv.x, Lv.y, Lv.z, Lv.w, Mv.x, Mv.y, Mv.z, Mv.w,
                                  Rv.x, Rv.y, Rv.z, Rv.w};
            const float aa[4] = {av.x, av.y, av.z, av.w};
#pragma unroll
            for (int dxi = 0; dxi < NP; ++dxi)
#pragma unroll
                for (int j = 0; j < 4; ++j) acc[dxi][j] += aa[j] * wv[dxi + j];
            p1 += PLANE;
            p2 += PLANE;
        }
    }

    float* reg0 = &lds[0 * 64 * LPAD + lane * LPAD];
    float* reg1 = &lds[1 * 64 * LPAD + lane * LPAD];
    if (w >= 2) {
        float* dst = (w == 2) ? reg0 : reg1;
#pragma unroll
        for (int dxi = 0; dxi < NP; ++dxi)
#pragma unroll
            for (int j = 0; j < 4; ++j) dst[dxi * 4 + j] = acc[dxi][j];
    }
    __syncthreads();
    if (w < 2) {
        const float* src = (w == 0) ? reg0 : reg1;
#pragma unroll
        for (int dxi = 0; dxi < NP; ++dxi)
#pragma unroll
            for (int j = 0; j < 4; ++j) acc[dxi][j] += src[dxi * 4 + j];
    }
    __syncthreads();
    if (w == 1) {
#pragma unroll
        for (int dxi = 0; dxi < NP; ++dxi)
#pragma unroll
            for (int j = 0; j < 4; ++j) reg0[dxi * 4 + j] = acc[dxi][j];
    }
    __syncthreads();
    if (w == 0) {
#pragma unroll
        for (int dxi = 0; dxi < NP; ++dxi)
#pragma unroll
            for (int j = 0; j < 4; ++j) acc[dxi][j] += reg0[dxi * 4 + j];
        float* ob = out + ((size_t)(b * 81 + dyi * 9) * NH + y) * NW + x0;
#pragma unroll
        for (int dxi = 0; dxi < NP; ++dxi) {
            *(float4*)ob = make_float4(acc[dxi][0], acc[dxi][1], acc[dxi][2], acc[dxi][3]);
            ob += PLANE;
        }
    }
}

extern "C" void kernel_launch(void* const* d_in, const int* in_sizes, int n_in,
                              void* d_out, int out_size, void* d_ws, size_t ws_size,
                              hipStream_t stream) {
    const float* f1 = (const float*)d_in[0];
    const float* f2 = (const float*)d_in[1];
    float* out = (float*)d_out;
    if (ws_size >= WS_NEED) {
        _Float16* ws = (_Float16*)d_ws;
        pack_f2<<<dim3(PACK_BLK, 1, 1), dim3(256, 1, 1), 0, stream>>>(f2, ws);
        costvol_mfma<<<dim3(MAIN_BLK, 1, 1), dim3(192, 1, 1), 0, stream>>>(f1, ws, out);
    } else {
        costvol_f32<<<dim3(1296, 1, 1), dim3(256, 1, 1), 0, stream>>>(f1, f2, out);
    }
}